// Round 17
// baseline (359.388 us; speedup 1.0000x reference)
//
#include <hip/hip_runtime.h>
#include <cstdint>
#include <cstddef>

typedef unsigned short u16;
typedef unsigned int u32;
typedef __attribute__((ext_vector_type(8))) short short8;   // 8 bf16 storage
typedef __attribute__((ext_vector_type(4))) short short4_;  // 4 bf16 storage
typedef __attribute__((ext_vector_type(2))) unsigned int u32x2;
typedef __attribute__((ext_vector_type(8))) __bf16 bf16x8;  // MFMA operand
typedef __attribute__((ext_vector_type(4))) float f32x4;

#define BB 2
#define SS 2048
#define DD 2048
#define HH 16
#define HD 128

__device__ __forceinline__ u16 f2bf(float x) {
  u32 u = __float_as_uint(x);
  u32 r = (u + 0x7FFFu + ((u >> 16) & 1u)) >> 16;  // RNE
  return (u16)r;
}
__device__ __forceinline__ float bf2f(u16 h) {
  return __uint_as_float(((u32)h) << 16);
}
__device__ __forceinline__ float exp2_hw(float x) {
  return __builtin_amdgcn_exp2f(x);  // v_exp_f32: D = 2^S0
}
__device__ __forceinline__ u32 cvtpk_bf16(float lo, float hi) {
  u32 r;
  asm("v_cvt_pk_bf16_f32 %0, %1, %2" : "=v"(r) : "v"(lo), "v"(hi));
  return r;  // low 16 = bf16(lo), high 16 = bf16(hi), RNE
}

__device__ __forceinline__ f32x4 mfma16x16x32(short8 a, short8 b, f32x4 c) {
  return __builtin_amdgcn_mfma_f32_16x16x32_bf16(
      __builtin_bit_cast(bf16x8, a), __builtin_bit_cast(bf16x8, b), c, 0, 0, 0);
}

__device__ __forceinline__ void gload_lds16(const void* g, void* l) {
  __builtin_amdgcn_global_load_lds(
      (const __attribute__((address_space(1))) void*)g,
      (__attribute__((address_space(3))) void*)l, 16, 0, 0);
}

// ---------------- fused cast: x (1048576 groups) + wq|wk|wv|wo (2097152 groups) ----------------
__global__ void cast_all_kernel(const float* __restrict__ x,
                                const float* __restrict__ wq, const float* __restrict__ wk,
                                const float* __restrict__ wv, const float* __restrict__ wo,
                                u16* __restrict__ xb, u16* __restrict__ wb) {
  int g = blockIdx.x * blockDim.x + threadIdx.x;   // 0 .. 3145727
  const float* s;
  u16* d;
  if (g < 1048576) {
    s = x + (size_t)g * 8;
    d = xb + (size_t)g * 8;
  } else {
    int wi = g - 1048576;
    int reg = wi >> 19;
    int off = wi & ((1 << 19) - 1);
    s = ((reg == 0) ? wq : (reg == 1) ? wk : (reg == 2) ? wv : wo) + (size_t)off * 8;
    d = wb + (size_t)wi * 8;   // wq,wk,wv,wo contiguous in ws
  }
  f32x4 a = *reinterpret_cast<const f32x4*>(s);
  f32x4 b = *reinterpret_cast<const f32x4*>(s + 4);
  short8 o;
  o[0] = (short)f2bf(a[0]); o[1] = (short)f2bf(a[1]);
  o[2] = (short)f2bf(a[2]); o[3] = (short)f2bf(a[3]);
  o[4] = (short)f2bf(b[0]); o[5] = (short)f2bf(b[1]);
  o[6] = (short)f2bf(b[2]); o[7] = (short)f2bf(b[3]);
  *reinterpret_cast<short8*>(d) = o;
}

// ---------------- NT GEMM: C[M,N] = A[M,K] * B[N,K]^T, m97 structure (r10-proven) ----------------
// MODE 0: bf16 out. MODE 1: f32 out. MODE 2: bf16 out + fused RoPE epilogue.
template <int MODE>
__global__ __launch_bounds__(256) void gemm_nt(const u16* __restrict__ A,
                                               const u16* __restrict__ Bw,
                                               void* __restrict__ Cout,
                                               const float* __restrict__ cosT,
                                               const float* __restrict__ sinT) {
  constexpr int K = 2048, N = 2048;
  __shared__ u16 As[128 * 32];
  __shared__ u16 Bs[128 * 32];
  const int t = threadIdx.x;
  const int w = t >> 6, l = t & 63;
  const int bm = blockIdx.x, bn = blockIdx.y;
  const int wm = (w >> 1) * 64, wn = (w & 1) * 64;
  const int lr = l & 15, lg = l >> 4;
  f32x4 acc[4][4] = {};

  for (int kk = 0; kk < K; kk += 32) {
    __syncthreads();
#pragma unroll
    for (int i = 0; i < 2; ++i) {
      int cb = (i * 4 + w) * 64;
      int chunk = cb + l;
      int row = chunk >> 2, kc = chunk & 3;
      gload_lds16(A + (size_t)(bm * 128 + row) * K + kk + kc * 8, (u16*)As + cb * 8);
      gload_lds16(Bw + (size_t)(bn * 128 + row) * K + kk + kc * 8, (u16*)Bs + cb * 8);
    }
    __syncthreads();
    short8 af[4], bf[4];
#pragma unroll
    for (int mi = 0; mi < 4; ++mi)
      af[mi] = *reinterpret_cast<const short8*>(&As[(wm + mi * 16 + lr) * 32 + lg * 8]);
#pragma unroll
    for (int ni = 0; ni < 4; ++ni)
      bf[ni] = *reinterpret_cast<const short8*>(&Bs[(wn + ni * 16 + lr) * 32 + lg * 8]);
#pragma unroll
    for (int mi = 0; mi < 4; ++mi)
#pragma unroll
      for (int ni = 0; ni < 4; ++ni)
        acc[mi][ni] = mfma16x16x32(af[mi], bf[ni], acc[mi][ni]);
  }
#pragma unroll
  for (int mi = 0; mi < 4; ++mi)
#pragma unroll
    for (int ni = 0; ni < 4; ++ni)
#pragma unroll
      for (int r = 0; r < 4; ++r) {
        int row = bm * 128 + wm + mi * 16 + lg * 4 + r;
        int col = bn * 128 + wn + ni * 16 + lr;
        float v = acc[mi][ni][r];
        if (MODE == 2) {
          // fused RoPE: lane l^1 holds col^1 of the same (mi,ni,r)
          float p = __shfl_xor(v, 1);
          int s = row & (SS - 1);
          int pi = (col & (HD - 1)) >> 1;
          float co = cosT[s * 64 + pi], sn = sinT[s * 64 + pi];
          v = (col & 1) ? (p * sn + v * co) : (v * co - p * sn);
        }
        if (MODE == 1)
          ((float*)Cout)[(size_t)row * N + col] = v;
        else
          ((u16*)Cout)[(size_t)row * N + col] = f2bf(v);
      }
}

// ---------------- Flash attention (causal) — 2 blocks/CU for barrier overlap ----------------
// Grid (16,32) = 512 blocks, 256 threads = 4 waves. Block ib owns q-tiles {ib, 31-ib}
// (uniform 33 tile-computes/wave). LDS 72KB -> 2 blocks/CU: one block computes through
// the other's staging drain (m114 wave-level overlap; the 1-block/CU config had none).
// Proven r10-r16 softmax_pv (swapped-operand QK^T, cvt_pk P-path, ones-MFMA rowsum,
// defer-max, exp2) untouched; staging uses the r6-proven 4-wave forms.
__global__ __launch_bounds__(256, 2) void attn_kernel(const u16* __restrict__ XQ,
                                                      const u16* __restrict__ XK,
                                                      const u16* __restrict__ XV,
                                                      u16* __restrict__ AO) {
  __shared__ u16 Ks[2][64 * 128];
  __shared__ u16 Vs[2][128 * 64];
  __shared__ u16 Ps[4][16 * 64];
  const int ib = blockIdx.x, bh = blockIdx.y;
  const int b = bh >> 4, h = bh & 15;
  const int t = threadIdx.x, w = t >> 6, l = t & 63;
  const int lr = l & 15, lg = l >> 4;
  const int qtA = ib;
  const int qtB = 31 - ib;
  const int qbA = qtA * 64 + w * 16;
  const int qbB = qtB * 64 + w * 16;
  const int nkv = 32 - ib;            // stage kv = 0 .. 31-ib (= qtB)
  const size_t rowbase = (size_t)b * SS;

  const short one_bf = (short)0x3F80;  // bf16 1.0
  const short8 onesf = {one_bf, one_bf, one_bf, one_bf, one_bf, one_bf, one_bf, one_bf};

  short8 qfA[4], qfB[4];
  {
    const u16* qpA = XQ + (rowbase + qbA + lr) * DD + h * HD + lg * 8;
    const u16* qpB = XQ + (rowbase + qbB + lr) * DD + h * HD + lg * 8;
#pragma unroll
    for (int ks = 0; ks < 4; ++ks) {
      qfA[ks] = *reinterpret_cast<const short8*>(qpA + ks * 32);
      qfB[ks] = *reinterpret_cast<const short8*>(qpB + ks * 32);
    }
  }

  f32x4 oA[8] = {}, oB[8] = {};
  f32x4 lsA = {}, lsB = {};
  float mrA = -1e30f, mrB = -1e30f;   // running max of q-row lr (log2 domain)

  char* Pw = (char*)Ps[w];
  short8 vr[4];
  const int vk0 = (t >> 4) * 4;   // 0..60 (4 k-rows per thread)
  const int vd0 = (t & 15) * 8;   // 0..120

  auto issueK = [&](int kvt, int buf) {
#pragma unroll
    for (int i2 = 0; i2 < 4; ++i2) {
      int cb = (w * 4 + i2) * 64;
      int chunk = cb + l;                  // 0..1023
      int krow = chunk >> 4, kc = chunk & 15;
      int lc = kc ^ (krow & 7);            // inverse swizzle on the source
      gload_lds16(XK + (rowbase + kvt * 64 + krow) * DD + h * HD + lc * 8,
                  (u16*)Ks[buf] + cb * 8);
    }
  };
  auto loadV = [&](int kvt) {
    const u16* vp = XV + (rowbase + kvt * 64 + vk0) * DD + h * HD + vd0;
#pragma unroll
    for (int r = 0; r < 4; ++r) vr[r] = *reinterpret_cast<const short8*>(vp + r * DD);
  };
  auto writeV = [&](int buf) {
    char* base = (char*)Vs[buf];
#pragma unroll
    for (int ii = 0; ii < 8; ++ii) {
      int d = vd0 + ii;
      int off = d * 128 + ((vk0 * 2) ^ ((((d >> 3) & 7) ^ (d & 7)) << 4));
      short4_ o4;
      o4[0] = vr[0][ii]; o4[1] = vr[1][ii]; o4[2] = vr[2][ii]; o4[3] = vr[3][ii];
      *reinterpret_cast<short4_*>(base + off) = o4;
    }
  };

  auto softmax_pv = [&](int kv, int cur, f32x4* sf, float& mr, f32x4& lsa, f32x4* o, int qbase) {
    const float scale2 = 0.12751743f;  // 1/sqrt(128) * log2(e) -> exp2 domain
    const bool diag = (kv == (qbase >> 6));
    const int kv0 = kv * 64;
    // sf[kt][r] = S[q=qbase+lr][k=kv0 + kt*16 + lg*4 + r]
    float pb[4][4];
#pragma unroll
    for (int kt = 0; kt < 4; ++kt)
#pragma unroll
      for (int r = 0; r < 4; ++r) {
        float s = sf[kt][r] * scale2;
        if (diag) {
          int kg = kv0 + kt * 16 + lg * 4 + r;
          int qg = qbase + lr;
          if (kg > qg) s = -1e30f;
        }
        pb[kt][r] = s;
      }
    // lazy defer-max (T13), log2 domain: threshold 11.54 = 8 nats
    float lm = pb[0][0];
#pragma unroll
    for (int kt = 0; kt < 4; ++kt)
#pragma unroll
      for (int r = 0; r < 4; ++r) lm = fmaxf(lm, pb[kt][r]);
    if (__any((int)(lm > mr + 11.54f))) {
      float m = lm;
      m = fmaxf(m, __shfl_xor(m, 16));
      m = fmaxf(m, __shfl_xor(m, 32));   // rows lr agree across lg groups
      float mn = fmaxf(mr, m);
      float sc = exp2_hw(mr - mn);       // scale for q-row lr
      mr = mn;
      // redistribute to O rows (lg*4+r): pull sc from lane with lr_src = lg*4+r
#pragma unroll
      for (int r = 0; r < 4; ++r) {
        float scr = __shfl(sc, (l & 48) + lg * 4 + r);
        lsa[r] *= scr;
#pragma unroll
        for (int dt = 0; dt < 8; ++dt) o[dt][r] *= scr;
      }
    }
#pragma unroll
    for (int kt = 0; kt < 4; ++kt)
#pragma unroll
      for (int r = 0; r < 4; ++r)
        pb[kt][r] = exp2_hw(pb[kt][r] - mr);
    // pack pairs (k consecutive) and write 8B per kt, row-swizzled
    char* Pr = Pw + lr * 128;
    const int swz = (lr & 7) << 4;
#pragma unroll
    for (int kt = 0; kt < 4; ++kt) {
      u32x2 wv;
      wv[0] = cvtpk_bf16(pb[kt][0], pb[kt][1]);
      wv[1] = cvtpk_bf16(pb[kt][2], pb[kt][3]);
      *reinterpret_cast<u32x2*>(Pr + ((kt * 32 + lg * 8) ^ swz)) = wv;
    }
    short8 pa[2];
#pragma unroll
    for (int ks = 0; ks < 2; ++ks)
      pa[ks] = *reinterpret_cast<const short8*>(Pr + ((ks * 64 + lg * 16) ^ swz));
    // row-sums via ones-fragment MFMA (lsa[r] = rowsum of q-row lg*4+r)
    lsa = mfma16x16x32(pa[0], onesf, lsa);
    lsa = mfma16x16x32(pa[1], onesf, lsa);
    // PV from LDS V^T
    const char* vbase = (const char*)Vs[cur];
    __builtin_amdgcn_s_setprio(1);
#pragma unroll
    for (int dt = 0; dt < 8; ++dt)
#pragma unroll
      for (int ks = 0; ks < 2; ++ks) {
        int d = dt * 16 + lr;
        int off = d * 128 + ((ks * 64 + lg * 16) ^ ((((d >> 3) & 7) ^ (d & 7)) << 4));
        short8 vf = *reinterpret_cast<const short8*>(vbase + off);
        o[dt] = mfma16x16x32(pa[ks], vf, o[dt]);
      }
    __builtin_amdgcn_s_setprio(0);
  };

  // prologue: stage tile 0
  issueK(0, 0);
  loadV(0);

  for (int kv = 0; kv < nkv; ++kv) {
    const int cur = kv & 1;
    writeV(cur);
    __syncthreads();   // drains vmcnt: Ks[cur] resident; Vs[cur] writes visible
    if (kv + 1 < nkv) { issueK(kv + 1, cur ^ 1); loadV(kv + 1); }

    const bool doA = (kv <= qtA);
    f32x4 sB[4], sA[4];
#pragma unroll
    for (int kt = 0; kt < 4; ++kt) {
      sB[kt] = f32x4{0.f, 0.f, 0.f, 0.f};
      sA[kt] = f32x4{0.f, 0.f, 0.f, 0.f};
    }
#pragma unroll
    for (int kt = 0; kt < 4; ++kt) {
      short8 kf[4];
#pragma unroll
      for (int ks = 0; ks < 4; ++ks) {
        int krow = kt * 16 + lr;
        int inner = (ks * 64 + lg * 16) ^ ((krow & 7) << 4);
        kf[ks] = *reinterpret_cast<const short8*>((const char*)Ks[cur] + krow * 256 + inner);
      }
      // SWAPPED operands: A = K-frag, B = Q-frag -> S^T in registers
#pragma unroll
      for (int ks = 0; ks < 4; ++ks) sB[kt] = mfma16x16x32(kf[ks], qfB[ks], sB[kt]);
      if (doA) {
#pragma unroll
        for (int ks = 0; ks < 4; ++ks) sA[kt] = mfma16x16x32(kf[ks], qfA[ks], sA[kt]);
      }
    }
    softmax_pv(kv, cur, sB, mrB, lsB, oB, qbB);
    if (doA) softmax_pv(kv, cur, sA, mrA, lsA, oA, qbA);
  }

  // epilogue (O rows = qbase + lg*4 + r)
#pragma unroll
  for (int r = 0; r < 4; ++r) {
    float invB = 1.0f / lsB[r];
    float invA = 1.0f / lsA[r];
    int qgB = qbB + lg * 4 + r;
    int qgA = qbA + lg * 4 + r;
    u16* opB = AO + (rowbase + qgB) * DD + h * HD + lr;
    u16* opA = AO + (rowbase + qgA) * DD + h * HD + lr;
#pragma unroll
    for (int dt = 0; dt < 8; ++dt) {
      opB[dt * 16] = f2bf(oB[dt][r] * invB);
      opA[dt * 16] = f2bf(oA[dt][r] * invA);
    }
  }
}

// ---------------- launch ----------------
extern "C" void kernel_launch(void* const* d_in, const int* in_sizes, int n_in,
                              void* d_out, int out_size, void* d_ws, size_t ws_size,
                              hipStream_t stream) {
  const float* x = (const float*)d_in[0];
  const float* wq = (const float*)d_in[1];
  const float* wk = (const float*)d_in[2];
  const float* wv = (const float*)d_in[3];
  const float* wo = (const float*)d_in[4];
  const float* cosT = (const float*)d_in[5];
  const float* sinT = (const float*)d_in[6];

  char* ws = (char*)d_ws;
  u16* xb  = (u16*)(ws);
  u16* wqb = (u16*)(ws + 16777216);   // wq,wk,wv,wo contiguous bf16 (4 x 8MB)
  u16* wkb = (u16*)(ws + 25165824);
  u16* wvb = (u16*)(ws + 33554432);
  u16* wob = (u16*)(ws + 41943040);
  u16* XQ  = (u16*)(ws + 50331648);
  u16* XK  = (u16*)(ws + 67108864);
  u16* XV  = (u16*)(ws + 83886080);
  u16* AO  = (u16*)(ws + 100663296);

  cast_all_kernel<<<12288, 256, 0, stream>>>(x, wq, wk, wv, wo, xb, wqb);

  dim3 gg(32, 16);
  gemm_nt<2><<<gg, 256, 0, stream>>>(xb, wqb, XQ, cosT, sinT);   // Q proj + RoPE
  gemm_nt<2><<<gg, 256, 0, stream>>>(xb, wkb, XK, cosT, sinT);   // K proj + RoPE
  gemm_nt<0><<<gg, 256, 0, stream>>>(xb, wvb, XV, nullptr, nullptr);

  attn_kernel<<<dim3(16, 32), 256, 0, stream>>>(XQ, XK, XV, AO);

  gemm_nt<1><<<gg, 256, 0, stream>>>(AO, wob, d_out, nullptr, nullptr);
}

// Round 18
// 311.240 us; speedup vs baseline: 1.1547x; 1.1547x over previous
//
#include <hip/hip_runtime.h>
#include <cstdint>
#include <cstddef>

typedef unsigned short u16;
typedef unsigned int u32;
typedef __attribute__((ext_vector_type(8))) short short8;   // 8 bf16 storage
typedef __attribute__((ext_vector_type(2))) unsigned int u32x2;
typedef __attribute__((ext_vector_type(8))) __bf16 bf16x8;  // MFMA operand
typedef __attribute__((ext_vector_type(4))) float f32x4;

#define BB 2
#define SS 2048
#define DD 2048
#define HH 16
#define HD 128

__device__ __forceinline__ u16 f2bf(float x) {
  u32 u = __float_as_uint(x);
  u32 r = (u + 0x7FFFu + ((u >> 16) & 1u)) >> 16;  // RNE
  return (u16)r;
}
__device__ __forceinline__ float bf2f(u16 h) {
  return __uint_as_float(((u32)h) << 16);
}
__device__ __forceinline__ float exp2_hw(float x) {
  return __builtin_amdgcn_exp2f(x);  // v_exp_f32: D = 2^S0
}
__device__ __forceinline__ u32 cvtpk_bf16(float lo, float hi) {
  u32 r;
  asm("v_cvt_pk_bf16_f32 %0, %1, %2" : "=v"(r) : "v"(lo), "v"(hi));
  return r;  // low 16 = bf16(lo), high 16 = bf16(hi), RNE
}

__device__ __forceinline__ f32x4 mfma16x16x32(short8 a, short8 b, f32x4 c) {
  return __builtin_amdgcn_mfma_f32_16x16x32_bf16(
      __builtin_bit_cast(bf16x8, a), __builtin_bit_cast(bf16x8, b), c, 0, 0, 0);
}

__device__ __forceinline__ void gload_lds16(const void* g, void* l) {
  __builtin_amdgcn_global_load_lds(
      (const __attribute__((address_space(1))) void*)g,
      (__attribute__((address_space(3))) void*)l, 16, 0, 0);
}

// ---------------- fused cast: x (1048576 groups) + wq|wk|wv|wo (2097152 groups) ----------------
__global__ void cast_all_kernel(const float* __restrict__ x,
                                const float* __restrict__ wq, const float* __restrict__ wk,
                                const float* __restrict__ wv, const float* __restrict__ wo,
                                u16* __restrict__ xb, u16* __restrict__ wb) {
  int g = blockIdx.x * blockDim.x + threadIdx.x;   // 0 .. 3145727
  const float* s;
  u16* d;
  if (g < 1048576) {
    s = x + (size_t)g * 8;
    d = xb + (size_t)g * 8;
  } else {
    int wi = g - 1048576;
    int reg = wi >> 19;
    int off = wi & ((1 << 19) - 1);
    s = ((reg == 0) ? wq : (reg == 1) ? wk : (reg == 2) ? wv : wo) + (size_t)off * 8;
    d = wb + (size_t)wi * 8;   // wq,wk,wv,wo contiguous in ws
  }
  f32x4 a = *reinterpret_cast<const f32x4*>(s);
  f32x4 b = *reinterpret_cast<const f32x4*>(s + 4);
  short8 o;
  o[0] = (short)f2bf(a[0]); o[1] = (short)f2bf(a[1]);
  o[2] = (short)f2bf(a[2]); o[3] = (short)f2bf(a[3]);
  o[4] = (short)f2bf(b[0]); o[5] = (short)f2bf(b[1]);
  o[6] = (short)f2bf(b[2]); o[7] = (short)f2bf(b[3]);
  *reinterpret_cast<short8*>(d) = o;
}

// ---------------- NT GEMM: C[M,N] = A[M,K] * B[N,K]^T, m97 structure (r10-proven) ----------------
// MODE 0: bf16 out. MODE 1: f32 out. MODE 2: bf16 out + fused RoPE epilogue.
template <int MODE>
__global__ __launch_bounds__(256) void gemm_nt(const u16* __restrict__ A,
                                               const u16* __restrict__ Bw,
                                               void* __restrict__ Cout,
                                               const float* __restrict__ cosT,
                                               const float* __restrict__ sinT) {
  constexpr int K = 2048, N = 2048;
  __shared__ u16 As[128 * 32];
  __shared__ u16 Bs[128 * 32];
  const int t = threadIdx.x;
  const int w = t >> 6, l = t & 63;
  const int bm = blockIdx.x, bn = blockIdx.y;
  const int wm = (w >> 1) * 64, wn = (w & 1) * 64;
  const int lr = l & 15, lg = l >> 4;
  f32x4 acc[4][4] = {};

  for (int kk = 0; kk < K; kk += 32) {
    __syncthreads();
#pragma unroll
    for (int i = 0; i < 2; ++i) {
      int cb = (i * 4 + w) * 64;
      int chunk = cb + l;
      int row = chunk >> 2, kc = chunk & 3;
      gload_lds16(A + (size_t)(bm * 128 + row) * K + kk + kc * 8, (u16*)As + cb * 8);
      gload_lds16(Bw + (size_t)(bn * 128 + row) * K + kk + kc * 8, (u16*)Bs + cb * 8);
    }
    __syncthreads();
    short8 af[4], bf[4];
#pragma unroll
    for (int mi = 0; mi < 4; ++mi)
      af[mi] = *reinterpret_cast<const short8*>(&As[(wm + mi * 16 + lr) * 32 + lg * 8]);
#pragma unroll
    for (int ni = 0; ni < 4; ++ni)
      bf[ni] = *reinterpret_cast<const short8*>(&Bs[(wn + ni * 16 + lr) * 32 + lg * 8]);
#pragma unroll
    for (int mi = 0; mi < 4; ++mi)
#pragma unroll
      for (int ni = 0; ni < 4; ++ni)
        acc[mi][ni] = mfma16x16x32(af[mi], bf[ni], acc[mi][ni]);
  }
#pragma unroll
  for (int mi = 0; mi < 4; ++mi)
#pragma unroll
    for (int ni = 0; ni < 4; ++ni)
#pragma unroll
      for (int r = 0; r < 4; ++r) {
        int row = bm * 128 + wm + mi * 16 + lg * 4 + r;
        int col = bn * 128 + wn + ni * 16 + lr;
        float v = acc[mi][ni][r];
        if (MODE == 2) {
          // fused RoPE: lane l^1 holds col^1 of the same (mi,ni,r)
          float p = __shfl_xor(v, 1);
          int s = row & (SS - 1);
          int pi = (col & (HD - 1)) >> 1;
          float co = cosT[s * 64 + pi], sn = sinT[s * 64 + pi];
          v = (col & 1) ? (p * sn + v * co) : (v * co - p * sn);
        }
        if (MODE == 1)
          ((float*)Cout)[(size_t)row * N + col] = v;
        else
          ((u16*)Cout)[(size_t)row * N + col] = f2bf(v);
      }
}

// ---------------- Flash attention (causal) — r16-exact structure (311us known-good) ----------------
// 512 threads = 8 waves. Block i owns q-tiles {2i, 2i+1, 30-2i, 31-2i} (uniform cost).
// Swapped-operand QK^T (S^T in regs), dbuf K+V, PV inside softmax_pv (per-tile V reads).
// setprio removed: 8-wave lockstep-barrier block = m190 regime where setprio is neutral/negative.
__global__ __launch_bounds__(512, 2) void attn_kernel(const u16* __restrict__ XQ,
                                                      const u16* __restrict__ XK,
                                                      const u16* __restrict__ XV,
                                                      u16* __restrict__ AO) {
  __shared__ u16 Ks[2][64 * 128];
  __shared__ u16 Vs[2][128 * 64];
  __shared__ u16 Ps[8][16 * 64];
  const int ib = blockIdx.x, bh = blockIdx.y;
  const int b = bh >> 4, h = bh & 15;
  const int t = threadIdx.x, w = t >> 6, l = t & 63;
  const int wh = w >> 2, wl = w & 3;
  const int lr = l & 15, lg = l >> 4;
  const int qtA = 2 * ib + wh;
  const int qtB = 31 - 2 * ib - wh;
  const int qbA = qtA * 64 + wl * 16;
  const int qbB = qtB * 64 + wl * 16;
  const int nkv = 32 - 2 * ib;            // stage kv = 0 .. 31-2*ib
  const size_t rowbase = (size_t)b * SS;

  const short one_bf = (short)0x3F80;  // bf16 1.0
  const short8 onesf = {one_bf, one_bf, one_bf, one_bf, one_bf, one_bf, one_bf, one_bf};

  short8 qfA[4], qfB[4];
  {
    const u16* qpA = XQ + (rowbase + qbA + lr) * DD + h * HD + lg * 8;
    const u16* qpB = XQ + (rowbase + qbB + lr) * DD + h * HD + lg * 8;
#pragma unroll
    for (int ks = 0; ks < 4; ++ks) {
      qfA[ks] = *reinterpret_cast<const short8*>(qpA + ks * 32);
      qfB[ks] = *reinterpret_cast<const short8*>(qpB + ks * 32);
    }
  }

  f32x4 oA[8] = {}, oB[8] = {};
  f32x4 lsA = {}, lsB = {};
  float mrA = -1e30f, mrB = -1e30f;   // running max of q-row lr (log2 domain)

  char* Pw = (char*)Ps[w];
  short8 vr[2];
  const int vk0 = (t >> 4) * 2;   // 0..62 (2 k-rows per thread)
  const int vd0 = (t & 15) * 8;   // 0..120

  auto issueK = [&](int kvt, int buf) {
#pragma unroll
    for (int i2 = 0; i2 < 2; ++i2) {
      int cb = (w * 2 + i2) * 64;
      int chunk = cb + l;                  // 0..1023
      int krow = chunk >> 4, kc = chunk & 15;
      int lc = kc ^ (krow & 7);            // inverse swizzle on the source
      gload_lds16(XK + (rowbase + kvt * 64 + krow) * DD + h * HD + lc * 8,
                  (u16*)Ks[buf] + cb * 8);
    }
  };
  auto loadV = [&](int kvt) {
    const u16* vp = XV + (rowbase + kvt * 64 + vk0) * DD + h * HD + vd0;
    vr[0] = *reinterpret_cast<const short8*>(vp);
    vr[1] = *reinterpret_cast<const short8*>(vp + DD);
  };
  auto writeV = [&](int buf) {
    char* base = (char*)Vs[buf];
#pragma unroll
    for (int ii = 0; ii < 8; ++ii) {
      int d = vd0 + ii;
      int off = d * 128 + ((vk0 * 2) ^ ((((d >> 3) & 7) ^ (d & 7)) << 4));
      u32 pk = (u32)(u16)vr[0][ii] | ((u32)(u16)vr[1][ii] << 16);
      *reinterpret_cast<u32*>(base + off) = pk;
    }
  };

  auto softmax_pv = [&](int kv, int cur, f32x4* sf, float& mr, f32x4& lsa, f32x4* o, int qbase) {
    const float scale2 = 0.12751743f;  // 1/sqrt(128) * log2(e) -> exp2 domain
    const bool diag = (kv == (qbase >> 6));
    const int kv0 = kv * 64;
    // sf[kt][r] = S[q=qbase+lr][k=kv0 + kt*16 + lg*4 + r]
    float pb[4][4];
#pragma unroll
    for (int kt = 0; kt < 4; ++kt)
#pragma unroll
      for (int r = 0; r < 4; ++r) {
        float s = sf[kt][r] * scale2;
        if (diag) {
          int kg = kv0 + kt * 16 + lg * 4 + r;
          int qg = qbase + lr;
          if (kg > qg) s = -1e30f;
        }
        pb[kt][r] = s;
      }
    // lazy defer-max (T13), log2 domain: threshold 11.54 = 8 nats
    float lm = pb[0][0];
#pragma unroll
    for (int kt = 0; kt < 4; ++kt)
#pragma unroll
      for (int r = 0; r < 4; ++r) lm = fmaxf(lm, pb[kt][r]);
    if (__any((int)(lm > mr + 11.54f))) {
      float m = lm;
      m = fmaxf(m, __shfl_xor(m, 16));
      m = fmaxf(m, __shfl_xor(m, 32));   // rows lr agree across lg groups
      float mn = fmaxf(mr, m);
      float sc = exp2_hw(mr - mn);       // scale for q-row lr
      mr = mn;
      // redistribute to O rows (lg*4+r): pull sc from lane with lr_src = lg*4+r
#pragma unroll
      for (int r = 0; r < 4; ++r) {
        float scr = __shfl(sc, (l & 48) + lg * 4 + r);
        lsa[r] *= scr;
#pragma unroll
        for (int dt = 0; dt < 8; ++dt) o[dt][r] *= scr;
      }
    }
#pragma unroll
    for (int kt = 0; kt < 4; ++kt)
#pragma unroll
      for (int r = 0; r < 4; ++r)
        pb[kt][r] = exp2_hw(pb[kt][r] - mr);
    // pack pairs (k consecutive) and write 8B per kt, row-swizzled
    char* Pr = Pw + lr * 128;
    const int swz = (lr & 7) << 4;
#pragma unroll
    for (int kt = 0; kt < 4; ++kt) {
      u32x2 wv;
      wv[0] = cvtpk_bf16(pb[kt][0], pb[kt][1]);
      wv[1] = cvtpk_bf16(pb[kt][2], pb[kt][3]);
      *reinterpret_cast<u32x2*>(Pr + ((kt * 32 + lg * 8) ^ swz)) = wv;
    }
    short8 pa[2];
#pragma unroll
    for (int ks = 0; ks < 2; ++ks)
      pa[ks] = *reinterpret_cast<const short8*>(Pr + ((ks * 64 + lg * 16) ^ swz));
    // row-sums via ones-fragment MFMA (lsa[r] = rowsum of q-row lg*4+r)
    lsa = mfma16x16x32(pa[0], onesf, lsa);
    lsa = mfma16x16x32(pa[1], onesf, lsa);
    // PV from LDS V^T
    const char* vbase = (const char*)Vs[cur];
#pragma unroll
    for (int dt = 0; dt < 8; ++dt)
#pragma unroll
      for (int ks = 0; ks < 2; ++ks) {
        int d = dt * 16 + lr;
        int off = d * 128 + ((ks * 64 + lg * 16) ^ ((((d >> 3) & 7) ^ (d & 7)) << 4));
        short8 vf = *reinterpret_cast<const short8*>(vbase + off);
        o[dt] = mfma16x16x32(pa[ks], vf, o[dt]);
      }
  };

  // prologue: stage tile 0
  issueK(0, 0);
  loadV(0);

  for (int kv = 0; kv < nkv; ++kv) {
    const int cur = kv & 1;
    writeV(cur);
    __syncthreads();   // drains vmcnt: Ks[cur] resident; Vs[cur] writes visible
    if (kv + 1 < nkv) { issueK(kv + 1, cur ^ 1); loadV(kv + 1); }

    const bool doB = (kv <= qtB);
    const bool doA = (kv <= qtA);
    if (doB) {
      f32x4 sB[4], sA[4];
#pragma unroll
      for (int kt = 0; kt < 4; ++kt) {
        sB[kt] = f32x4{0.f, 0.f, 0.f, 0.f};
        sA[kt] = f32x4{0.f, 0.f, 0.f, 0.f};
      }
#pragma unroll
      for (int kt = 0; kt < 4; ++kt) {
        short8 kf[4];
#pragma unroll
        for (int ks = 0; ks < 4; ++ks) {
          int krow = kt * 16 + lr;
          int inner = (ks * 64 + lg * 16) ^ ((krow & 7) << 4);
          kf[ks] = *reinterpret_cast<const short8*>((const char*)Ks[cur] + krow * 256 + inner);
        }
        // SWAPPED operands: A = K-frag, B = Q-frag -> S^T in registers
#pragma unroll
        for (int ks = 0; ks < 4; ++ks) sB[kt] = mfma16x16x32(kf[ks], qfB[ks], sB[kt]);
        if (doA) {
#pragma unroll
          for (int ks = 0; ks < 4; ++ks) sA[kt] = mfma16x16x32(kf[ks], qfA[ks], sA[kt]);
        }
      }
      softmax_pv(kv, cur, sB, mrB, lsB, oB, qbB);
      if (doA) softmax_pv(kv, cur, sA, mrA, lsA, oA, qbA);
    }
  }

  // epilogue (O rows = qbase + lg*4 + r)
#pragma unroll
  for (int r = 0; r < 4; ++r) {
    float invB = 1.0f / lsB[r];
    float invA = 1.0f / lsA[r];
    int qgB = qbB + lg * 4 + r;
    int qgA = qbA + lg * 4 + r;
    u16* opB = AO + (rowbase + qgB) * DD + h * HD + lr;
    u16* opA = AO + (rowbase + qgA) * DD + h * HD + lr;
#pragma unroll
    for (int dt = 0; dt < 8; ++dt) {
      opB[dt * 16] = f2bf(oB[dt][r] * invB);
      opA[dt * 16] = f2bf(oA[dt][r] * invA);
    }
  }
}

// ---------------- launch ----------------
extern "C" void kernel_launch(void* const* d_in, const int* in_sizes, int n_in,
                              void* d_out, int out_size, void* d_ws, size_t ws_size,
                              hipStream_t stream) {
  const float* x = (const float*)d_in[0];
  const float* wq = (const float*)d_in[1];
  const float* wk = (const float*)d_in[2];
  const float* wv = (const float*)d_in[3];
  const float* wo = (const float*)d_in[4];
  const float* cosT = (const float*)d_in[5];
  const float* sinT = (const float*)d_in[6];

  char* ws = (char*)d_ws;
  u16* xb  = (u16*)(ws);
  u16* wqb = (u16*)(ws + 16777216);   // wq,wk,wv,wo contiguous bf16 (4 x 8MB)
  u16* wkb = (u16*)(ws + 25165824);
  u16* wvb = (u16*)(ws + 33554432);
  u16* wob = (u16*)(ws + 41943040);
  u16* XQ  = (u16*)(ws + 50331648);
  u16* XK  = (u16*)(ws + 67108864);
  u16* XV  = (u16*)(ws + 83886080);
  u16* AO  = (u16*)(ws + 100663296);

  cast_all_kernel<<<12288, 256, 0, stream>>>(x, wq, wk, wv, wo, xb, wqb);

  dim3 gg(32, 16);
  gemm_nt<2><<<gg, 256, 0, stream>>>(xb, wqb, XQ, cosT, sinT);   // Q proj + RoPE
  gemm_nt<2><<<gg, 256, 0, stream>>>(xb, wkb, XK, cosT, sinT);   // K proj + RoPE
  gemm_nt<0><<<gg, 256, 0, stream>>>(xb, wvb, XV, nullptr, nullptr);

  attn_kernel<<<dim3(8, 32), 512, 0, stream>>>(XQ, XK, XV, AO);

  gemm_nt<1><<<gg, 256, 0, stream>>>(AO, wob, d_out, nullptr, nullptr);
}

// Round 19
// 287.452 us; speedup vs baseline: 1.2503x; 1.0828x over previous
//
#include <hip/hip_runtime.h>
#include <cstdint>
#include <cstddef>

typedef unsigned short u16;
typedef unsigned int u32;
typedef __attribute__((ext_vector_type(8))) short short8;   // 8 bf16 storage
typedef __attribute__((ext_vector_type(2))) unsigned int u32x2;
typedef __attribute__((ext_vector_type(8))) __bf16 bf16x8;  // MFMA operand
typedef __attribute__((ext_vector_type(4))) float f32x4;

#define BB 2
#define SS 2048
#define DD 2048
#define HH 16
#define HD 128

__device__ __forceinline__ u16 f2bf(float x) {
  u32 u = __float_as_uint(x);
  u32 r = (u + 0x7FFFu + ((u >> 16) & 1u)) >> 16;  // RNE
  return (u16)r;
}
__device__ __forceinline__ float bf2f(u16 h) {
  return __uint_as_float(((u32)h) << 16);
}
__device__ __forceinline__ float exp2_hw(float x) {
  return __builtin_amdgcn_exp2f(x);  // v_exp_f32: D = 2^S0
}
__device__ __forceinline__ u32 cvtpk_bf16(float lo, float hi) {
  u32 r;
  asm("v_cvt_pk_bf16_f32 %0, %1, %2" : "=v"(r) : "v"(lo), "v"(hi));
  return r;  // low 16 = bf16(lo), high 16 = bf16(hi), RNE
}

__device__ __forceinline__ f32x4 mfma16x16x32(short8 a, short8 b, f32x4 c) {
  return __builtin_amdgcn_mfma_f32_16x16x32_bf16(
      __builtin_bit_cast(bf16x8, a), __builtin_bit_cast(bf16x8, b), c, 0, 0, 0);
}

__device__ __forceinline__ void gload_lds16(const void* g, void* l) {
  __builtin_amdgcn_global_load_lds(
      (const __attribute__((address_space(1))) void*)g,
      (__attribute__((address_space(3))) void*)l, 16, 0, 0);
}

// ---------------- fused cast: x (1048576 groups) + wq|wk|wv|wo (2097152 groups) ----------------
__global__ void cast_all_kernel(const float* __restrict__ x,
                                const float* __restrict__ wq, const float* __restrict__ wk,
                                const float* __restrict__ wv, const float* __restrict__ wo,
                                u16* __restrict__ xb, u16* __restrict__ wb) {
  int g = blockIdx.x * blockDim.x + threadIdx.x;   // 0 .. 3145727
  const float* s;
  u16* d;
  if (g < 1048576) {
    s = x + (size_t)g * 8;
    d = xb + (size_t)g * 8;
  } else {
    int wi = g - 1048576;
    int reg = wi >> 19;
    int off = wi & ((1 << 19) - 1);
    s = ((reg == 0) ? wq : (reg == 1) ? wk : (reg == 2) ? wv : wo) + (size_t)off * 8;
    d = wb + (size_t)wi * 8;   // wq,wk,wv,wo contiguous in ws
  }
  f32x4 a = *reinterpret_cast<const f32x4*>(s);
  f32x4 b = *reinterpret_cast<const f32x4*>(s + 4);
  short8 o;
  o[0] = (short)f2bf(a[0]); o[1] = (short)f2bf(a[1]);
  o[2] = (short)f2bf(a[2]); o[3] = (short)f2bf(a[3]);
  o[4] = (short)f2bf(b[0]); o[5] = (short)f2bf(b[1]);
  o[6] = (short)f2bf(b[2]); o[7] = (short)f2bf(b[3]);
  *reinterpret_cast<short8*>(d) = o;
}

// ---------------- NT GEMM: C[M,N] = A[M,K] * B[N,K]^T, BK=64 + XOR-swizzled LDS ----------------
// m97 wave layout (4 waves, 64x64 each), BK=64 halves barrier count per FLOP (occupancy is
// grid-capped at 2 blocks/CU, so 32KB LDS costs nothing). 128B rows would be 16-way bank
// conflicts -> attn-proven staging: pre-swizzled gload source (lc = kc ^ (row&7)), linear
// LDS dest, XOR on frag read. Bank = (slot*4+word)%32, row-independent = minimal.
// MODE 0: bf16 out. MODE 1: f32 out. MODE 2: bf16 out + fused RoPE epilogue.
template <int MODE>
__global__ __launch_bounds__(256) void gemm_nt(const u16* __restrict__ A,
                                               const u16* __restrict__ Bw,
                                               void* __restrict__ Cout,
                                               const float* __restrict__ cosT,
                                               const float* __restrict__ sinT) {
  constexpr int K = 2048, N = 2048;
  __shared__ u16 As[128 * 64];
  __shared__ u16 Bs[128 * 64];
  const int t = threadIdx.x;
  const int w = t >> 6, l = t & 63;
  const int bm = blockIdx.x, bn = blockIdx.y;
  const int wm = (w >> 1) * 64, wn = (w & 1) * 64;
  const int lr = l & 15, lg = l >> 4;
  f32x4 acc[4][4] = {};

  for (int kk = 0; kk < K; kk += 64) {
    __syncthreads();
    // stage A,B: 128 rows x 64 cols = 1024 x 16B chunks each; 4 chunks/thread each
#pragma unroll
    for (int i = 0; i < 4; ++i) {
      int cb = (i * 4 + w) * 64;        // wave-uniform chunk base
      int chunk = cb + l;               // 0..1023; row = chunk>>3, kc = chunk&7
      int row = chunk >> 3, kc = chunk & 7;
      int lc = kc ^ (row & 7);          // inverse swizzle on the source
      gload_lds16(A + (size_t)(bm * 128 + row) * K + kk + lc * 8, (u16*)As + cb * 8);
      gload_lds16(Bw + (size_t)(bn * 128 + row) * K + kk + lc * 8, (u16*)Bs + cb * 8);
    }
    __syncthreads();
#pragma unroll
    for (int kh = 0; kh < 2; ++kh) {
      short8 af[4], bf[4];
#pragma unroll
      for (int mi = 0; mi < 4; ++mi) {
        int row = wm + mi * 16 + lr;
        int inner = (kh * 64 + lg * 16) ^ ((row & 7) << 4);
        af[mi] = *reinterpret_cast<const short8*>((const char*)As + row * 128 + inner);
      }
#pragma unroll
      for (int ni = 0; ni < 4; ++ni) {
        int row = wn + ni * 16 + lr;
        int inner = (kh * 64 + lg * 16) ^ ((row & 7) << 4);
        bf[ni] = *reinterpret_cast<const short8*>((const char*)Bs + row * 128 + inner);
      }
#pragma unroll
      for (int mi = 0; mi < 4; ++mi)
#pragma unroll
        for (int ni = 0; ni < 4; ++ni)
          acc[mi][ni] = mfma16x16x32(af[mi], bf[ni], acc[mi][ni]);
    }
  }
#pragma unroll
  for (int mi = 0; mi < 4; ++mi)
#pragma unroll
    for (int ni = 0; ni < 4; ++ni)
#pragma unroll
      for (int r = 0; r < 4; ++r) {
        int row = bm * 128 + wm + mi * 16 + lg * 4 + r;
        int col = bn * 128 + wn + ni * 16 + lr;
        float v = acc[mi][ni][r];
        if (MODE == 2) {
          // fused RoPE: lane l^1 holds col^1 of the same (mi,ni,r)
          float p = __shfl_xor(v, 1);
          int s = row & (SS - 1);
          int pi = (col & (HD - 1)) >> 1;
          float co = cosT[s * 64 + pi], sn = sinT[s * 64 + pi];
          v = (col & 1) ? (p * sn + v * co) : (v * co - p * sn);
        }
        if (MODE == 1)
          ((float*)Cout)[(size_t)row * N + col] = v;
        else
          ((u16*)Cout)[(size_t)row * N + col] = f2bf(v);
      }
}

// ---------------- Flash attention (causal) — r16/r18-exact structure (311us known-good) ----------------
// 512 threads = 8 waves. Block i owns q-tiles {2i, 2i+1, 30-2i, 31-2i} (uniform cost).
// Swapped-operand QK^T (S^T in regs), dbuf K+V, PV inside softmax_pv (per-tile V reads).
__global__ __launch_bounds__(512, 2) void attn_kernel(const u16* __restrict__ XQ,
                                                      const u16* __restrict__ XK,
                                                      const u16* __restrict__ XV,
                                                      u16* __restrict__ AO) {
  __shared__ u16 Ks[2][64 * 128];
  __shared__ u16 Vs[2][128 * 64];
  __shared__ u16 Ps[8][16 * 64];
  const int ib = blockIdx.x, bh = blockIdx.y;
  const int b = bh >> 4, h = bh & 15;
  const int t = threadIdx.x, w = t >> 6, l = t & 63;
  const int wh = w >> 2, wl = w & 3;
  const int lr = l & 15, lg = l >> 4;
  const int qtA = 2 * ib + wh;
  const int qtB = 31 - 2 * ib - wh;
  const int qbA = qtA * 64 + wl * 16;
  const int qbB = qtB * 64 + wl * 16;
  const int nkv = 32 - 2 * ib;            // stage kv = 0 .. 31-2*ib
  const size_t rowbase = (size_t)b * SS;

  const short one_bf = (short)0x3F80;  // bf16 1.0
  const short8 onesf = {one_bf, one_bf, one_bf, one_bf, one_bf, one_bf, one_bf, one_bf};

  short8 qfA[4], qfB[4];
  {
    const u16* qpA = XQ + (rowbase + qbA + lr) * DD + h * HD + lg * 8;
    const u16* qpB = XQ + (rowbase + qbB + lr) * DD + h * HD + lg * 8;
#pragma unroll
    for (int ks = 0; ks < 4; ++ks) {
      qfA[ks] = *reinterpret_cast<const short8*>(qpA + ks * 32);
      qfB[ks] = *reinterpret_cast<const short8*>(qpB + ks * 32);
    }
  }

  f32x4 oA[8] = {}, oB[8] = {};
  f32x4 lsA = {}, lsB = {};
  float mrA = -1e30f, mrB = -1e30f;   // running max of q-row lr (log2 domain)

  char* Pw = (char*)Ps[w];
  short8 vr[2];
  const int vk0 = (t >> 4) * 2;   // 0..62 (2 k-rows per thread)
  const int vd0 = (t & 15) * 8;   // 0..120

  auto issueK = [&](int kvt, int buf) {
#pragma unroll
    for (int i2 = 0; i2 < 2; ++i2) {
      int cb = (w * 2 + i2) * 64;
      int chunk = cb + l;                  // 0..1023
      int krow = chunk >> 4, kc = chunk & 15;
      int lc = kc ^ (krow & 7);            // inverse swizzle on the source
      gload_lds16(XK + (rowbase + kvt * 64 + krow) * DD + h * HD + lc * 8,
                  (u16*)Ks[buf] + cb * 8);
    }
  };
  auto loadV = [&](int kvt) {
    const u16* vp = XV + (rowbase + kvt * 64 + vk0) * DD + h * HD + vd0;
    vr[0] = *reinterpret_cast<const short8*>(vp);
    vr[1] = *reinterpret_cast<const short8*>(vp + DD);
  };
  auto writeV = [&](int buf) {
    char* base = (char*)Vs[buf];
#pragma unroll
    for (int ii = 0; ii < 8; ++ii) {
      int d = vd0 + ii;
      int off = d * 128 + ((vk0 * 2) ^ ((((d >> 3) & 7) ^ (d & 7)) << 4));
      u32 pk = (u32)(u16)vr[0][ii] | ((u32)(u16)vr[1][ii] << 16);
      *reinterpret_cast<u32*>(base + off) = pk;
    }
  };

  auto softmax_pv = [&](int kv, int cur, f32x4* sf, float& mr, f32x4& lsa, f32x4* o, int qbase) {
    const float scale2 = 0.12751743f;  // 1/sqrt(128) * log2(e) -> exp2 domain
    const bool diag = (kv == (qbase >> 6));
    const int kv0 = kv * 64;
    // sf[kt][r] = S[q=qbase+lr][k=kv0 + kt*16 + lg*4 + r]
    float pb[4][4];
#pragma unroll
    for (int kt = 0; kt < 4; ++kt)
#pragma unroll
      for (int r = 0; r < 4; ++r) {
        float s = sf[kt][r] * scale2;
        if (diag) {
          int kg = kv0 + kt * 16 + lg * 4 + r;
          int qg = qbase + lr;
          if (kg > qg) s = -1e30f;
        }
        pb[kt][r] = s;
      }
    // lazy defer-max (T13), log2 domain: threshold 11.54 = 8 nats
    float lm = pb[0][0];
#pragma unroll
    for (int kt = 0; kt < 4; ++kt)
#pragma unroll
      for (int r = 0; r < 4; ++r) lm = fmaxf(lm, pb[kt][r]);
    if (__any((int)(lm > mr + 11.54f))) {
      float m = lm;
      m = fmaxf(m, __shfl_xor(m, 16));
      m = fmaxf(m, __shfl_xor(m, 32));   // rows lr agree across lg groups
      float mn = fmaxf(mr, m);
      float sc = exp2_hw(mr - mn);       // scale for q-row lr
      mr = mn;
      // redistribute to O rows (lg*4+r): pull sc from lane with lr_src = lg*4+r
#pragma unroll
      for (int r = 0; r < 4; ++r) {
        float scr = __shfl(sc, (l & 48) + lg * 4 + r);
        lsa[r] *= scr;
#pragma unroll
        for (int dt = 0; dt < 8; ++dt) o[dt][r] *= scr;
      }
    }
#pragma unroll
    for (int kt = 0; kt < 4; ++kt)
#pragma unroll
      for (int r = 0; r < 4; ++r)
        pb[kt][r] = exp2_hw(pb[kt][r] - mr);
    // pack pairs (k consecutive) and write 8B per kt, row-swizzled
    char* Pr = Pw + lr * 128;
    const int swz = (lr & 7) << 4;
#pragma unroll
    for (int kt = 0; kt < 4; ++kt) {
      u32x2 wv;
      wv[0] = cvtpk_bf16(pb[kt][0], pb[kt][1]);
      wv[1] = cvtpk_bf16(pb[kt][2], pb[kt][3]);
      *reinterpret_cast<u32x2*>(Pr + ((kt * 32 + lg * 8) ^ swz)) = wv;
    }
    short8 pa[2];
#pragma unroll
    for (int ks = 0; ks < 2; ++ks)
      pa[ks] = *reinterpret_cast<const short8*>(Pr + ((ks * 64 + lg * 16) ^ swz));
    // row-sums via ones-fragment MFMA (lsa[r] = rowsum of q-row lg*4+r)
    lsa = mfma16x16x32(pa[0], onesf, lsa);
    lsa = mfma16x16x32(pa[1], onesf, lsa);
    // PV from LDS V^T
    const char* vbase = (const char*)Vs[cur];
#pragma unroll
    for (int dt = 0; dt < 8; ++dt)
#pragma unroll
      for (int ks = 0; ks < 2; ++ks) {
        int d = dt * 16 + lr;
        int off = d * 128 + ((ks * 64 + lg * 16) ^ ((((d >> 3) & 7) ^ (d & 7)) << 4));
        short8 vf = *reinterpret_cast<const short8*>(vbase + off);
        o[dt] = mfma16x16x32(pa[ks], vf, o[dt]);
      }
  };

  // prologue: stage tile 0
  issueK(0, 0);
  loadV(0);

  for (int kv = 0; kv < nkv; ++kv) {
    const int cur = kv & 1;
    writeV(cur);
    __syncthreads();   // drains vmcnt: Ks[cur] resident; Vs[cur] writes visible
    if (kv + 1 < nkv) { issueK(kv + 1, cur ^ 1); loadV(kv + 1); }

    const bool doB = (kv <= qtB);
    const bool doA = (kv <= qtA);
    if (doB) {
      f32x4 sB[4], sA[4];
#pragma unroll
      for (int kt = 0; kt < 4; ++kt) {
        sB[kt] = f32x4{0.f, 0.f, 0.f, 0.f};
        sA[kt] = f32x4{0.f, 0.f, 0.f, 0.f};
      }
#pragma unroll
      for (int kt = 0; kt < 4; ++kt) {
        short8 kf[4];
#pragma unroll
        for (int ks = 0; ks < 4; ++ks) {
          int krow = kt * 16 + lr;
          int inner = (ks * 64 + lg * 16) ^ ((krow & 7) << 4);
          kf[ks] = *reinterpret_cast<const short8*>((const char*)Ks[cur] + krow * 256 + inner);
        }
        // SWAPPED operands: A = K-frag, B = Q-frag -> S^T in registers
#pragma unroll
        for (int ks = 0; ks < 4; ++ks) sB[kt] = mfma16x16x32(kf[ks], qfB[ks], sB[kt]);
        if (doA) {
#pragma unroll
          for (int ks = 0; ks < 4; ++ks) sA[kt] = mfma16x16x32(kf[ks], qfA[ks], sA[kt]);
        }
      }
      softmax_pv(kv, cur, sB, mrB, lsB, oB, qbB);
      if (doA) softmax_pv(kv, cur, sA, mrA, lsA, oA, qbA);
    }
  }

  // epilogue (O rows = qbase + lg*4 + r)
#pragma unroll
  for (int r = 0; r < 4; ++r) {
    float invB = 1.0f / lsB[r];
    float invA = 1.0f / lsA[r];
    int qgB = qbB + lg * 4 + r;
    int qgA = qbA + lg * 4 + r;
    u16* opB = AO + (rowbase + qgB) * DD + h * HD + lr;
    u16* opA = AO + (rowbase + qgA) * DD + h * HD + lr;
#pragma unroll
    for (int dt = 0; dt < 8; ++dt) {
      opB[dt * 16] = f2bf(oB[dt][r] * invB);
      opA[dt * 16] = f2bf(oA[dt][r] * invA);
    }
  }
}

// ---------------- launch ----------------
extern "C" void kernel_launch(void* const* d_in, const int* in_sizes, int n_in,
                              void* d_out, int out_size, void* d_ws, size_t ws_size,
                              hipStream_t stream) {
  const float* x = (const float*)d_in[0];
  const float* wq = (const float*)d_in[1];
  const float* wk = (const float*)d_in[2];
  const float* wv = (const float*)d_in[3];
  const float* wo = (const float*)d_in[4];
  const float* cosT = (const float*)d_in[5];
  const float* sinT = (const float*)d_in[6];

  char* ws = (char*)d_ws;
  u16* xb  = (u16*)(ws);
  u16* wqb = (u16*)(ws + 16777216);   // wq,wk,wv,wo contiguous bf16 (4 x 8MB)
  u16* wkb = (u16*)(ws + 25165824);
  u16* wvb = (u16*)(ws + 33554432);
  u16* wob = (u16*)(ws + 41943040);
  u16* XQ  = (u16*)(ws + 50331648);
  u16* XK  = (u16*)(ws + 67108864);
  u16* XV  = (u16*)(ws + 83886080);
  u16* AO  = (u16*)(ws + 100663296);

  cast_all_kernel<<<12288, 256, 0, stream>>>(x, wq, wk, wv, wo, xb, wqb);

  dim3 gg(32, 16);
  gemm_nt<2><<<gg, 256, 0, stream>>>(xb, wqb, XQ, cosT, sinT);   // Q proj + RoPE
  gemm_nt<2><<<gg, 256, 0, stream>>>(xb, wkb, XK, cosT, sinT);   // K proj + RoPE
  gemm_nt<0><<<gg, 256, 0, stream>>>(xb, wvb, XV, nullptr, nullptr);

  attn_kernel<<<dim3(8, 32), 512, 0, stream>>>(XQ, XK, XV, AO);

  gemm_nt<1><<<gg, 256, 0, stream>>>(AO, wob, d_out, nullptr, nullptr);
}

// Round 20
// 271.391 us; speedup vs baseline: 1.3242x; 1.0592x over previous
//
#include <hip/hip_runtime.h>
#include <cstdint>
#include <cstddef>

typedef unsigned short u16;
typedef unsigned int u32;
typedef __attribute__((ext_vector_type(8))) short short8;   // 8 bf16 storage
typedef __attribute__((ext_vector_type(2))) unsigned int u32x2;
typedef __attribute__((ext_vector_type(8))) __bf16 bf16x8;  // MFMA operand
typedef __attribute__((ext_vector_type(4))) float f32x4;

#define BB 2
#define SS 2048
#define DD 2048
#define HH 16
#define HD 128

__device__ __forceinline__ u16 f2bf(float x) {
  u32 u = __float_as_uint(x);
  u32 r = (u + 0x7FFFu + ((u >> 16) & 1u)) >> 16;  // RNE
  return (u16)r;
}
__device__ __forceinline__ float bf2f(u16 h) {
  return __uint_as_float(((u32)h) << 16);
}
__device__ __forceinline__ float exp2_hw(float x) {
  return __builtin_amdgcn_exp2f(x);  // v_exp_f32: D = 2^S0
}
__device__ __forceinline__ u32 cvtpk_bf16(float lo, float hi) {
  u32 r;
  asm("v_cvt_pk_bf16_f32 %0, %1, %2" : "=v"(r) : "v"(lo), "v"(hi));
  return r;  // low 16 = bf16(lo), high 16 = bf16(hi), RNE
}

__device__ __forceinline__ f32x4 mfma16x16x32(short8 a, short8 b, f32x4 c) {
  return __builtin_amdgcn_mfma_f32_16x16x32_bf16(
      __builtin_bit_cast(bf16x8, a), __builtin_bit_cast(bf16x8, b), c, 0, 0, 0);
}

__device__ __forceinline__ void gload_lds16(const void* g, void* l) {
  __builtin_amdgcn_global_load_lds(
      (const __attribute__((address_space(1))) void*)g,
      (__attribute__((address_space(3))) void*)l, 16, 0, 0);
}

// ---------------- fused cast: x (1048576 groups) + wq|wk|wv|wo (2097152 groups) ----------------
__global__ void cast_all_kernel(const float* __restrict__ x,
                                const float* __restrict__ wq, const float* __restrict__ wk,
                                const float* __restrict__ wv, const float* __restrict__ wo,
                                u16* __restrict__ xb, u16* __restrict__ wb) {
  int g = blockIdx.x * blockDim.x + threadIdx.x;   // 0 .. 3145727
  const float* s;
  u16* d;
  if (g < 1048576) {
    s = x + (size_t)g * 8;
    d = xb + (size_t)g * 8;
  } else {
    int wi = g - 1048576;
    int reg = wi >> 19;
    int off = wi & ((1 << 19) - 1);
    s = ((reg == 0) ? wq : (reg == 1) ? wk : (reg == 2) ? wv : wo) + (size_t)off * 8;
    d = wb + (size_t)wi * 8;   // wq,wk,wv,wo contiguous in ws
  }
  f32x4 a = *reinterpret_cast<const f32x4*>(s);
  f32x4 b = *reinterpret_cast<const f32x4*>(s + 4);
  short8 o;
  o[0] = (short)f2bf(a[0]); o[1] = (short)f2bf(a[1]);
  o[2] = (short)f2bf(a[2]); o[3] = (short)f2bf(a[3]);
  o[4] = (short)f2bf(b[0]); o[5] = (short)f2bf(b[1]);
  o[6] = (short)f2bf(b[2]); o[7] = (short)f2bf(b[3]);
  *reinterpret_cast<short8*>(d) = o;
}

// ---------------- NT GEMM: C[M,N] = A[M,K] * B[N,K]^T, BK=128 + XOR-swizzled LDS ----------------
// m97 wave layout (4 waves, 64x64 each). BK=128 quarters barrier count vs BK=32 (occupancy
// is grid-capped at 2 blocks/CU; 64KB LDS/block x2 = 128KB <= 160KB, so no occupancy cost).
// Staging: pre-swizzled gload source lc = kc ^ (row&7) (bijective within each 8-slot half),
// linear LDS dest; frag read inner = (kh*64+lg*16) ^ ((row&7)<<4) -> reads global slot
// kh*4+lg exactly. Bank pattern per instruction identical to the proven BK=64 (2-way, free).
// MODE 0: bf16 out. MODE 1: f32 out. MODE 2: bf16 out + fused RoPE epilogue.
template <int MODE>
__global__ __launch_bounds__(256) void gemm_nt(const u16* __restrict__ A,
                                               const u16* __restrict__ Bw,
                                               void* __restrict__ Cout,
                                               const float* __restrict__ cosT,
                                               const float* __restrict__ sinT) {
  constexpr int K = 2048, N = 2048;
  __shared__ u16 As[128 * 128];
  __shared__ u16 Bs[128 * 128];
  const int t = threadIdx.x;
  const int w = t >> 6, l = t & 63;
  const int bm = blockIdx.x, bn = blockIdx.y;
  const int wm = (w >> 1) * 64, wn = (w & 1) * 64;
  const int lr = l & 15, lg = l >> 4;
  f32x4 acc[4][4] = {};

  for (int kk = 0; kk < K; kk += 128) {
    __syncthreads();
    // stage A,B: 128 rows x 128 cols = 2048 x 16B chunks each; 8 chunks/thread each
#pragma unroll
    for (int i = 0; i < 8; ++i) {
      int cb = (i * 4 + w) * 64;        // wave-uniform chunk base
      int chunk = cb + l;               // 0..2047; row = chunk>>4, kc = chunk&15
      int row = chunk >> 4, kc = chunk & 15;
      int lc = kc ^ (row & 7);          // inverse swizzle on the source
      gload_lds16(A + (size_t)(bm * 128 + row) * K + kk + lc * 8, (u16*)As + cb * 8);
      gload_lds16(Bw + (size_t)(bn * 128 + row) * K + kk + lc * 8, (u16*)Bs + cb * 8);
    }
    __syncthreads();
#pragma unroll
    for (int kh = 0; kh < 4; ++kh) {
      short8 af[4], bf[4];
#pragma unroll
      for (int mi = 0; mi < 4; ++mi) {
        int row = wm + mi * 16 + lr;
        int inner = (kh * 64 + lg * 16) ^ ((row & 7) << 4);
        af[mi] = *reinterpret_cast<const short8*>((const char*)As + row * 256 + inner);
      }
#pragma unroll
      for (int ni = 0; ni < 4; ++ni) {
        int row = wn + ni * 16 + lr;
        int inner = (kh * 64 + lg * 16) ^ ((row & 7) << 4);
        bf[ni] = *reinterpret_cast<const short8*>((const char*)Bs + row * 256 + inner);
      }
#pragma unroll
      for (int mi = 0; mi < 4; ++mi)
#pragma unroll
        for (int ni = 0; ni < 4; ++ni)
          acc[mi][ni] = mfma16x16x32(af[mi], bf[ni], acc[mi][ni]);
    }
  }
#pragma unroll
  for (int mi = 0; mi < 4; ++mi)
#pragma unroll
    for (int ni = 0; ni < 4; ++ni)
#pragma unroll
      for (int r = 0; r < 4; ++r) {
        int row = bm * 128 + wm + mi * 16 + lg * 4 + r;
        int col = bn * 128 + wn + ni * 16 + lr;
        float v = acc[mi][ni][r];
        if (MODE == 2) {
          // fused RoPE: lane l^1 holds col^1 of the same (mi,ni,r)
          float p = __shfl_xor(v, 1);
          int s = row & (SS - 1);
          int pi = (col & (HD - 1)) >> 1;
          float co = cosT[s * 64 + pi], sn = sinT[s * 64 + pi];
          v = (col & 1) ? (p * sn + v * co) : (v * co - p * sn);
        }
        if (MODE == 1)
          ((float*)Cout)[(size_t)row * N + col] = v;
        else
          ((u16*)Cout)[(size_t)row * N + col] = f2bf(v);
      }
}

// ---------------- Flash attention (causal) — r16/r18/r19-exact structure ----------------
// 512 threads = 8 waves. Block i owns q-tiles {2i, 2i+1, 30-2i, 31-2i} (uniform cost).
// Swapped-operand QK^T (S^T in regs), dbuf K+V, PV inside softmax_pv (per-tile V reads).
__global__ __launch_bounds__(512, 2) void attn_kernel(const u16* __restrict__ XQ,
                                                      const u16* __restrict__ XK,
                                                      const u16* __restrict__ XV,
                                                      u16* __restrict__ AO) {
  __shared__ u16 Ks[2][64 * 128];
  __shared__ u16 Vs[2][128 * 64];
  __shared__ u16 Ps[8][16 * 64];
  const int ib = blockIdx.x, bh = blockIdx.y;
  const int b = bh >> 4, h = bh & 15;
  const int t = threadIdx.x, w = t >> 6, l = t & 63;
  const int wh = w >> 2, wl = w & 3;
  const int lr = l & 15, lg = l >> 4;
  const int qtA = 2 * ib + wh;
  const int qtB = 31 - 2 * ib - wh;
  const int qbA = qtA * 64 + wl * 16;
  const int qbB = qtB * 64 + wl * 16;
  const int nkv = 32 - 2 * ib;            // stage kv = 0 .. 31-2*ib
  const size_t rowbase = (size_t)b * SS;

  const short one_bf = (short)0x3F80;  // bf16 1.0
  const short8 onesf = {one_bf, one_bf, one_bf, one_bf, one_bf, one_bf, one_bf, one_bf};

  short8 qfA[4], qfB[4];
  {
    const u16* qpA = XQ + (rowbase + qbA + lr) * DD + h * HD + lg * 8;
    const u16* qpB = XQ + (rowbase + qbB + lr) * DD + h * HD + lg * 8;
#pragma unroll
    for (int ks = 0; ks < 4; ++ks) {
      qfA[ks] = *reinterpret_cast<const short8*>(qpA + ks * 32);
      qfB[ks] = *reinterpret_cast<const short8*>(qpB + ks * 32);
    }
  }

  f32x4 oA[8] = {}, oB[8] = {};
  f32x4 lsA = {}, lsB = {};
  float mrA = -1e30f, mrB = -1e30f;   // running max of q-row lr (log2 domain)

  char* Pw = (char*)Ps[w];
  short8 vr[2];
  const int vk0 = (t >> 4) * 2;   // 0..62 (2 k-rows per thread)
  const int vd0 = (t & 15) * 8;   // 0..120

  auto issueK = [&](int kvt, int buf) {
#pragma unroll
    for (int i2 = 0; i2 < 2; ++i2) {
      int cb = (w * 2 + i2) * 64;
      int chunk = cb + l;                  // 0..1023
      int krow = chunk >> 4, kc = chunk & 15;
      int lc = kc ^ (krow & 7);            // inverse swizzle on the source
      gload_lds16(XK + (rowbase + kvt * 64 + krow) * DD + h * HD + lc * 8,
                  (u16*)Ks[buf] + cb * 8);
    }
  };
  auto loadV = [&](int kvt) {
    const u16* vp = XV + (rowbase + kvt * 64 + vk0) * DD + h * HD + vd0;
    vr[0] = *reinterpret_cast<const short8*>(vp);
    vr[1] = *reinterpret_cast<const short8*>(vp + DD);
  };
  auto writeV = [&](int buf) {
    char* base = (char*)Vs[buf];
#pragma unroll
    for (int ii = 0; ii < 8; ++ii) {
      int d = vd0 + ii;
      int off = d * 128 + ((vk0 * 2) ^ ((((d >> 3) & 7) ^ (d & 7)) << 4));
      u32 pk = (u32)(u16)vr[0][ii] | ((u32)(u16)vr[1][ii] << 16);
      *reinterpret_cast<u32*>(base + off) = pk;
    }
  };

  auto softmax_pv = [&](int kv, int cur, f32x4* sf, float& mr, f32x4& lsa, f32x4* o, int qbase) {
    const float scale2 = 0.12751743f;  // 1/sqrt(128) * log2(e) -> exp2 domain
    const bool diag = (kv == (qbase >> 6));
    const int kv0 = kv * 64;
    // sf[kt][r] = S[q=qbase+lr][k=kv0 + kt*16 + lg*4 + r]
    float pb[4][4];
#pragma unroll
    for (int kt = 0; kt < 4; ++kt)
#pragma unroll
      for (int r = 0; r < 4; ++r) {
        float s = sf[kt][r] * scale2;
        if (diag) {
          int kg = kv0 + kt * 16 + lg * 4 + r;
          int qg = qbase + lr;
          if (kg > qg) s = -1e30f;
        }
        pb[kt][r] = s;
      }
    // lazy defer-max (T13), log2 domain: threshold 11.54 = 8 nats
    float lm = pb[0][0];
#pragma unroll
    for (int kt = 0; kt < 4; ++kt)
#pragma unroll
      for (int r = 0; r < 4; ++r) lm = fmaxf(lm, pb[kt][r]);
    if (__any((int)(lm > mr + 11.54f))) {
      float m = lm;
      m = fmaxf(m, __shfl_xor(m, 16));
      m = fmaxf(m, __shfl_xor(m, 32));   // rows lr agree across lg groups
      float mn = fmaxf(mr, m);
      float sc = exp2_hw(mr - mn);       // scale for q-row lr
      mr = mn;
      // redistribute to O rows (lg*4+r): pull sc from lane with lr_src = lg*4+r
#pragma unroll
      for (int r = 0; r < 4; ++r) {
        float scr = __shfl(sc, (l & 48) + lg * 4 + r);
        lsa[r] *= scr;
#pragma unroll
        for (int dt = 0; dt < 8; ++dt) o[dt][r] *= scr;
      }
    }
#pragma unroll
    for (int kt = 0; kt < 4; ++kt)
#pragma unroll
      for (int r = 0; r < 4; ++r)
        pb[kt][r] = exp2_hw(pb[kt][r] - mr);
    // pack pairs (k consecutive) and write 8B per kt, row-swizzled
    char* Pr = Pw + lr * 128;
    const int swz = (lr & 7) << 4;
#pragma unroll
    for (int kt = 0; kt < 4; ++kt) {
      u32x2 wv;
      wv[0] = cvtpk_bf16(pb[kt][0], pb[kt][1]);
      wv[1] = cvtpk_bf16(pb[kt][2], pb[kt][3]);
      *reinterpret_cast<u32x2*>(Pr + ((kt * 32 + lg * 8) ^ swz)) = wv;
    }
    short8 pa[2];
#pragma unroll
    for (int ks = 0; ks < 2; ++ks)
      pa[ks] = *reinterpret_cast<const short8*>(Pr + ((ks * 64 + lg * 16) ^ swz));
    // row-sums via ones-fragment MFMA (lsa[r] = rowsum of q-row lg*4+r)
    lsa = mfma16x16x32(pa[0], onesf, lsa);
    lsa = mfma16x16x32(pa[1], onesf, lsa);
    // PV from LDS V^T
    const char* vbase = (const char*)Vs[cur];
#pragma unroll
    for (int dt = 0; dt < 8; ++dt)
#pragma unroll
      for (int ks = 0; ks < 2; ++ks) {
        int d = dt * 16 + lr;
        int off = d * 128 + ((ks * 64 + lg * 16) ^ ((((d >> 3) & 7) ^ (d & 7)) << 4));
        short8 vf = *reinterpret_cast<const short8*>(vbase + off);
        o[dt] = mfma16x16x32(pa[ks], vf, o[dt]);
      }
  };

  // prologue: stage tile 0
  issueK(0, 0);
  loadV(0);

  for (int kv = 0; kv < nkv; ++kv) {
    const int cur = kv & 1;
    writeV(cur);
    __syncthreads();   // drains vmcnt: Ks[cur] resident; Vs[cur] writes visible
    if (kv + 1 < nkv) { issueK(kv + 1, cur ^ 1); loadV(kv + 1); }

    const bool doB = (kv <= qtB);
    const bool doA = (kv <= qtA);
    if (doB) {
      f32x4 sB[4], sA[4];
#pragma unroll
      for (int kt = 0; kt < 4; ++kt) {
        sB[kt] = f32x4{0.f, 0.f, 0.f, 0.f};
        sA[kt] = f32x4{0.f, 0.f, 0.f, 0.f};
      }
#pragma unroll
      for (int kt = 0; kt < 4; ++kt) {
        short8 kf[4];
#pragma unroll
        for (int ks = 0; ks < 4; ++ks) {
          int krow = kt * 16 + lr;
          int inner = (ks * 64 + lg * 16) ^ ((krow & 7) << 4);
          kf[ks] = *reinterpret_cast<const short8*>((const char*)Ks[cur] + krow * 256 + inner);
        }
        // SWAPPED operands: A = K-frag, B = Q-frag -> S^T in registers
#pragma unroll
        for (int ks = 0; ks < 4; ++ks) sB[kt] = mfma16x16x32(kf[ks], qfB[ks], sB[kt]);
        if (doA) {
#pragma unroll
          for (int ks = 0; ks < 4; ++ks) sA[kt] = mfma16x16x32(kf[ks], qfA[ks], sA[kt]);
        }
      }
      softmax_pv(kv, cur, sB, mrB, lsB, oB, qbB);
      if (doA) softmax_pv(kv, cur, sA, mrA, lsA, oA, qbA);
    }
  }

  // epilogue (O rows = qbase + lg*4 + r)
#pragma unroll
  for (int r = 0; r < 4; ++r) {
    float invB = 1.0f / lsB[r];
    float invA = 1.0f / lsA[r];
    int qgB = qbB + lg * 4 + r;
    int qgA = qbA + lg * 4 + r;
    u16* opB = AO + (rowbase + qgB) * DD + h * HD + lr;
    u16* opA = AO + (rowbase + qgA) * DD + h * HD + lr;
#pragma unroll
    for (int dt = 0; dt < 8; ++dt) {
      opB[dt * 16] = f2bf(oB[dt][r] * invB);
      opA[dt * 16] = f2bf(oA[dt][r] * invA);
    }
  }
}

// ---------------- launch ----------------
extern "C" void kernel_launch(void* const* d_in, const int* in_sizes, int n_in,
                              void* d_out, int out_size, void* d_ws, size_t ws_size,
                              hipStream_t stream) {
  const float* x = (const float*)d_in[0];
  const float* wq = (const float*)d_in[1];
  const float* wk = (const float*)d_in[2];
  const float* wv = (const float*)d_in[3];
  const float* wo = (const float*)d_in[4];
  const float* cosT = (const float*)d_in[5];
  const float* sinT = (const float*)d_in[6];

  char* ws = (char*)d_ws;
  u16* xb  = (u16*)(ws);
  u16* wqb = (u16*)(ws + 16777216);   // wq,wk,wv,wo contiguous bf16 (4 x 8MB)
  u16* wkb = (u16*)(ws + 25165824);
  u16* wvb = (u16*)(ws + 33554432);
  u16* wob = (u16*)(ws + 41943040);
  u16* XQ  = (u16*)(ws + 50331648);
  u16* XK  = (u16*)(ws + 67108864);
  u16* XV  = (u16*)(ws + 83886080);
  u16* AO  = (u16*)(ws + 100663296);

  cast_all_kernel<<<12288, 256, 0, stream>>>(x, wq, wk, wv, wo, xb, wqb);

  dim3 gg(32, 16);
  gemm_nt<2><<<gg, 256, 0, stream>>>(xb, wqb, XQ, cosT, sinT);   // Q proj + RoPE
  gemm_nt<2><<<gg, 256, 0, stream>>>(xb, wkb, XK, cosT, sinT);   // K proj + RoPE
  gemm_nt<0><<<gg, 256, 0, stream>>>(xb, wvb, XV, nullptr, nullptr);

  attn_kernel<<<dim3(8, 32), 512, 0, stream>>>(XQ, XK, XV, AO);

  gemm_nt<1><<<gg, 256, 0, stream>>>(AO, wob, d_out, nullptr, nullptr);
}